// Round 1
// baseline (281.532 us; speedup 1.0000x reference)
//
#include <hip/hip_runtime.h>
#include <cstdint>
#include <cstddef>

// Problem constants (from reference setup_inputs)
#define BB   8
#define NN   2048
#define DD   16
#define HHH  64
#define KK   32
#define CAP  96          // max within-R candidates kept (mean ~36, Poisson tail safe)
#define DT_C 0.01f
#define R2_C (0.08f * 0.08f)

#define WPB   8                 // waves per block (1 particle per wave)
#define BLOCK (WPB * 64)

// Bit-deterministic distance: identical codegen in both kernels (no fma contraction),
// so k_grad's d2 matches k_neighbors' cutoff values exactly.
__device__ __forceinline__ float dist2(float px, float py, float qx, float qy) {
    float dx = __fsub_rn(px, qx);
    float dy = __fsub_rn(py, qy);
    return __fadd_rn(__fmul_rn(dx, dx), __fmul_rn(dy, dy));
}

// sech^2(z) = 1 - tanh^2(z) = 4a/(1+a)^2, a = exp(-2|z|)  (even in z, no copysign)
__device__ __forceinline__ float sech2(float z) {
    float a = __expf(-2.f * fabsf(z));
    float b = 1.f + a;
    return a / (b * b);   // caller multiplies by 4*v[h]
}

// Prep (once per launch): v = W2 @ Wout, and compact pos0[i] = x0[i][:2]
__global__ void k_prep(const float* __restrict__ x,
                       const float* __restrict__ W2, const float* __restrict__ Wout,
                       float* __restrict__ v, float* __restrict__ pos) {
    int gid = blockIdx.x * blockDim.x + threadIdx.x;   // 64*512 = 32768 = B*N*2
    pos[gid] = x[(gid >> 1) * DD + (gid & 1)];
    if (blockIdx.x == 0 && threadIdx.x < HHH) {
        float acc = 0.f;
        for (int c = 0; c < 32; c++) acc = fmaf(W2[threadIdx.x * 32 + c], Wout[c], acc);
        v[threadIdx.x] = acc;
    }
}

// Kernel 1 per step: per particle p (one wave):
//  - A_p[h] = x_p @ W1[:16], D_p[h] = x_p @ W1[16:]  -> AD table
//  - collect candidates {j : d2 < R^2, j != p} via ballot compaction
//  - cutoff_p = 32nd smallest candidate d2 (rank-select), else R^2
//  - emit candidate list with fwd flag (d2 <= cutoff_p) in bit 15
__global__ __launch_bounds__(BLOCK) void k_neighbors(
    const float* __restrict__ x, const float* __restrict__ pos,
    const float* __restrict__ W1,
    unsigned short* __restrict__ nbr, int* __restrict__ cntArr,
    float* __restrict__ cutArr, float* __restrict__ AD) {
    __shared__ float sPos[2 * NN];          // 16 KB
    __shared__ float sW1[2 * DD * HHH];     // 8 KB
    __shared__ float sD[WPB][CAP];
    __shared__ unsigned short sJ[WPB][CAP];

    int tid = threadIdx.x;
    int w = tid >> 6, lane = tid & 63;
    int p = blockIdx.x * WPB + w;
    int pl = p & (NN - 1);
    int bbase = (p >> 11) << 11;

    for (int t = tid; t < 2 * NN; t += BLOCK) sPos[t] = pos[bbase * 2 + t];
    for (int t = tid; t < 2 * DD * HHH; t += BLOCK) sW1[t] = W1[t];
    __syncthreads();

    // ---- A/D precompute (lane = h) ----
    float xv = (lane < DD) ? x[(size_t)p * DD + lane] : 0.f;
    float A = 0.f, Dv = 0.f;
#pragma unroll
    for (int f = 0; f < DD; f++) {
        float xf = __shfl(xv, f);
        A  = fmaf(xf, sW1[f * HHH + lane], A);
        Dv = fmaf(xf, sW1[(DD + f) * HHH + lane], Dv);
    }
    AD[(size_t)p * 128 + lane] = A;
    AD[(size_t)p * 128 + 64 + lane] = Dv;

    // ---- candidate collection (32 chunks of 64 distances) ----
    float px = sPos[2 * pl], py = sPos[2 * pl + 1];
    int cnt = 0;
    for (int c0 = 0; c0 < NN; c0 += 64) {
        int j = c0 + lane;
        float d2 = dist2(px, py, sPos[2 * j], sPos[2 * j + 1]);
        bool hit = (d2 < R2_C) && (j != pl);
        unsigned long long m = __ballot(hit);
        int idx = cnt + (int)__popcll(m & ((1ull << lane) - 1ull));
        if (hit && idx < CAP) { sD[w][idx] = d2; sJ[w][idx] = (unsigned short)j; }
        cnt += (int)__popcll(m);
    }
    if (cnt > CAP) cnt = CAP;
    __threadfence_block();   // wave-local LDS RAW drain

    // ---- cutoff = K-th smallest (rank select over <=96 values) ----
    float cutoff = R2_C;
    if (cnt > KK) {
        const float INF = 1e30f;
        float e0 = (lane < cnt) ? sD[w][lane] : INF;
        float e1 = (lane + 64 < cnt) ? sD[w][lane + 64] : INF;
        int r0 = 0, q0 = 0, r1 = 0, q1 = 0;
        for (int k = 0; k < cnt; k++) {
            float val = sD[w][k];      // uniform LDS broadcast
            r0 += (val < e0); q0 += (val == e0);
            r1 += (val < e1); q1 += (val == e1);
        }
        bool c0 = (r0 <= KK - 1) && (r0 + q0 > KK - 1);
        bool c1 = (r1 <= KK - 1) && (r1 + q1 > KK - 1);
        float cand = c0 ? e0 : (c1 ? e1 : INF);
#pragma unroll
        for (int off = 32; off; off >>= 1) cand = fminf(cand, __shfl_xor(cand, off));
        cutoff = cand;
    }
    if (lane == 0) { cutArr[p] = cutoff; cntArr[p] = cnt; }
    for (int c = lane; c < cnt; c += 64) {
        bool fwd = (sD[w][c] <= cutoff);
        nbr[(size_t)p * CAP + c] = (unsigned short)(sJ[w][c] | (fwd ? 0x8000 : 0));
    }
}

// Kernel 2 per step: per particle p (one wave, lane = h):
//  S1[h] = sum_{j in nbr(p)}  v[h]*sech2(A_p+D_j+b1)   (fwd edges, flag from k1)
//  S2[h] = sum_{j: p in nbr(j)} v[h]*sech2(A_j+D_p+b1) (rev edges: d2 <= cutoff_j)
//  grad_p[f] = sum_h W1[f][h]*S1[h] + W1[16+f][h]*S2[h]
//  x_next[p] = x_cur[p] - DT*grad_p  (also refresh compact pos array)
__global__ __launch_bounds__(BLOCK) void k_grad(
    const float* __restrict__ x, const float* __restrict__ pos,
    const float* __restrict__ cutArr, const int* __restrict__ cntArr,
    const unsigned short* __restrict__ nbr, const float* __restrict__ AD,
    const float* __restrict__ W1, const float* __restrict__ b1,
    const float* __restrict__ vArr,
    float* __restrict__ xOut, float* __restrict__ posOut) {
    __shared__ float sPos[2 * NN];         // 16 KB
    __shared__ float sCut[NN];             // 8 KB
    __shared__ float sW1t[2 * DD * HHH];   // 8 KB, transposed: sW1t[h*32+f] = W1[f][h]
    __shared__ float sS[WPB][128];         // 4 KB

    int tid = threadIdx.x;
    int w = tid >> 6, h = tid & 63;
    int p = blockIdx.x * WPB + w;
    int pl = p & (NN - 1);
    int bbase = (p >> 11) << 11;

    for (int t = tid; t < 2 * NN; t += BLOCK) sPos[t] = pos[bbase * 2 + t];
    for (int t = tid; t < NN; t += BLOCK) sCut[t] = cutArr[bbase + t];
    for (int t = tid; t < 2 * DD * HHH; t += BLOCK) {
        int f = t >> 6, hh = t & 63;
        sW1t[hh * 32 + f] = W1[t];
    }
    __syncthreads();

    float Ap  = AD[(size_t)p * 128 + h];
    float Dp  = AD[(size_t)p * 128 + 64 + h];
    float b1h = b1[h];
    float vh4 = 4.f * vArr[h];
    float px = sPos[2 * pl], py = sPos[2 * pl + 1];
    int cnt = cntArr[p];
    int j0 = (h < cnt) ? (int)nbr[(size_t)p * CAP + h] : 0;
    int j1 = (h + 64 < cnt) ? (int)nbr[(size_t)p * CAP + 64 + h] : 0;

    float S1 = 0.f, S2 = 0.f;
    for (int c = 0; c < cnt; c++) {
        int jp = __shfl((c < 64) ? j0 : j1, c & 63);   // uniform candidate
        int jl = jp & (NN - 1);
        float d2 = dist2(px, py, sPos[2 * jl], sPos[2 * jl + 1]);
        const float* ADj = AD + (size_t)(bbase + jl) * 128;
        if (jp & 0x8000) {                 // fwd: j in nbr(p)
            float z = Ap + ADj[64 + h] + b1h;
            S1 += vh4 * sech2(z);
        }
        if (d2 <= sCut[jl]) {              // rev: p in nbr(j)
            float z = ADj[h] + Dp + b1h;
            S2 += vh4 * sech2(z);
        }
    }

    sS[w][h] = S1;
    sS[w][64 + h] = S2;
    __syncthreads();

    float g = 0.f;
    if (h < 32) {                          // lane l<16: W1_top@S1 ; 16<=l<32: W1_bot@S2
        const float* Sv = &sS[w][(h < 16) ? 0 : 64];
        float acc = 0.f;
        for (int hh = 0; hh < 64; hh++) acc = fmaf(sW1t[hh * 32 + h], Sv[hh], acc);
        g = acc;
    }
    float g2 = __shfl(g, (h + 16) & 63);
    if (h < DD) {
        float xn = x[(size_t)p * DD + h] - DT_C * (g + g2);
        xOut[(size_t)p * DD + h] = xn;
        if (h < 2) posOut[p * 2 + h] = xn;
    }
}

extern "C" void kernel_launch(void* const* d_in, const int* in_sizes, int n_in,
                              void* d_out, int out_size, void* d_ws, size_t ws_size,
                              hipStream_t stream) {
    const float* x0   = (const float*)d_in[0];
    const float* W1   = (const float*)d_in[1];
    const float* b1   = (const float*)d_in[2];
    const float* W2   = (const float*)d_in[3];
    const float* Wout = (const float*)d_in[5];
    float* out = (float*)d_out;

    // workspace layout (floats); total ~13 MB
    float* ws   = (float*)d_ws;
    float* v    = ws;                      // 64
    float* posA = ws + 64;                 // 32768
    float* posB = posA + 32768;            // 32768
    float* x1   = posB + 32768;            // 262144
    float* AD   = x1 + 262144;             // 2097152 (16384 x 128)
    float* cut  = AD + 2097152;            // 16384
    int*   cnt  = (int*)(cut + 16384);     // 16384
    unsigned short* nbr = (unsigned short*)(cnt + 16384);  // 16384*96

    dim3 blk(BLOCK);
    const int NBLK = (BB * NN) / WPB;      // 2048

    k_prep<<<64, 512, 0, stream>>>(x0, W2, Wout, v, posA);
    // step 0: x0 -> x1
    k_neighbors<<<NBLK, blk, 0, stream>>>(x0, posA, W1, nbr, cnt, cut, AD);
    k_grad<<<NBLK, blk, 0, stream>>>(x0, posA, cut, cnt, nbr, AD, W1, b1, v, x1, posB);
    // step 1: x1 -> out
    k_neighbors<<<NBLK, blk, 0, stream>>>(x1, posB, W1, nbr, cnt, cut, AD);
    k_grad<<<NBLK, blk, 0, stream>>>(x1, posB, cut, cnt, nbr, AD, W1, b1, v, out, posA);
}

// Round 2
// 233.377 us; speedup vs baseline: 1.2063x; 1.2063x over previous
//
#include <hip/hip_runtime.h>
#include <cstdint>
#include <cstddef>

// Problem constants (from reference setup_inputs)
#define BB   8
#define NN   2048
#define DD   16
#define HHH  64
#define KK   32
#define CAP  96          // max within-R candidates kept (mean ~36, Poisson tail safe)
#define DT_C 0.01f
#define R2_C (0.08f * 0.08f)

#define WPB   8                 // waves per block (1 particle per wave)
#define BLOCK (WPB * 64)

// Bit-deterministic distance: identical codegen in both kernels (no fma contraction),
// so k_grad's d2 matches k_neighbors' cutoff values exactly. Also bitwise symmetric.
__device__ __forceinline__ float dist2(float px, float py, float qx, float qy) {
    float dx = __fsub_rn(px, qx);
    float dy = __fsub_rn(py, qy);
    return __fadd_rn(__fmul_rn(dx, dx), __fmul_rn(dy, dy));
}

// Kernel 1 per step, one wave per particle p:
//  - A_p[h] = x_p @ W1[:16], D_p[h] = x_p @ W1[16:]  -> packed float2 AD table
//  - collect candidates {j : d2 < R^2, j != p} via ballot+mbcnt compaction (j-ascending)
//  - cutoff_p = 32nd smallest candidate d2 (bitonic sort; LDS rank-select if cnt>64)
//  - emit candidate list with fwd flag (d2 <= cutoff_p) in bit 15
template <bool FIRST>
__global__ __launch_bounds__(BLOCK) void k_neighbors(
    const float* __restrict__ x, const float* __restrict__ pos,
    const float* __restrict__ W1,
    unsigned short* __restrict__ nbr, int* __restrict__ cntArr,
    float* __restrict__ cutArr, float2* __restrict__ AD) {
    __shared__ float sPos[2 * NN];          // 16 KB
    __shared__ float sW1[2 * DD * HHH];     // 8 KB
    __shared__ float2 sDJ[WPB][CAP];        // 6 KB packed {d2, j-bits}

    int tid = threadIdx.x;
    int w = tid >> 6, lane = tid & 63;
    int p = blockIdx.x * WPB + w;
    int pl = p & (NN - 1);
    int bbase = (p >> 11) << 11;

    if (FIRST) {
        for (int t = tid; t < 2 * NN; t += BLOCK)
            sPos[t] = x[(size_t)(bbase + (t >> 1)) * DD + (t & 1)];
    } else {
        for (int t = tid; t < 2 * NN; t += BLOCK) sPos[t] = pos[bbase * 2 + t];
    }
    for (int t = tid; t < 2 * DD * HHH; t += BLOCK) sW1[t] = W1[t];
    __syncthreads();

    // ---- A/D precompute (lane = h), packed store ----
    float xv = (lane < DD) ? x[(size_t)p * DD + lane] : 0.f;
    float A = 0.f, Dv = 0.f;
#pragma unroll
    for (int f = 0; f < DD; f++) {
        float xf = __shfl(xv, f);
        A  = fmaf(xf, sW1[f * HHH + lane], A);
        Dv = fmaf(xf, sW1[(DD + f) * HHH + lane], Dv);
    }
    AD[((size_t)p << 6) + lane] = make_float2(A, Dv);

    // ---- candidate collection (32 chunks of 64 distances) ----
    float px = sPos[2 * pl], py = sPos[2 * pl + 1];
    const float2* sPos2 = (const float2*)sPos;
    int cnt = 0;
    for (int c0 = 0; c0 < NN; c0 += 64) {
        int j = c0 + lane;
        float2 q = sPos2[j];
        float d2 = dist2(px, py, q.x, q.y);
        bool hit = (d2 < R2_C) && (j != pl);
        unsigned long long m = __ballot(hit);
        int idx = cnt + (int)__builtin_amdgcn_mbcnt_hi(
                      (unsigned)(m >> 32),
                      __builtin_amdgcn_mbcnt_lo((unsigned)m, 0u));
        if (hit && idx < CAP)
            sDJ[w][idx] = make_float2(d2, __uint_as_float((unsigned)j));
        cnt += (int)__popcll(m);
    }
    if (cnt > CAP) cnt = CAP;
    __threadfence_block();   // wave-local LDS RAW drain

    // ---- cutoff = K-th smallest candidate d2 (value-exact selection) ----
    float cutoff = R2_C;
    if (cnt > KK) {
        const float INF = 1e30f;
        if (cnt <= 64) {
            float v = (lane < cnt) ? sDJ[w][lane].x : INF;
#pragma unroll
            for (int k = 2; k <= 64; k <<= 1) {
#pragma unroll
                for (int j = k >> 1; j > 0; j >>= 1) {
                    float pv = __shfl_xor(v, j);
                    bool up = ((lane & k) == 0);
                    bool takeMin = (((lane & j) == 0) == up);
                    v = takeMin ? fminf(v, pv) : fmaxf(v, pv);
                }
            }
            cutoff = __shfl(v, KK - 1);   // ascending sort -> 32nd smallest
        } else {                          // cnt in (64,96]: ~never, kept for correctness
            float e0 = (lane < cnt) ? sDJ[w][lane].x : INF;
            float e1 = (lane + 64 < cnt) ? sDJ[w][lane + 64].x : INF;
            int r0 = 0, q0 = 0, r1 = 0, q1 = 0;
            for (int k = 0; k < cnt; k++) {
                float val = sDJ[w][k].x;
                r0 += (val < e0); q0 += (val == e0);
                r1 += (val < e1); q1 += (val == e1);
            }
            bool c0 = (r0 <= KK - 1) && (r0 + q0 > KK - 1);
            bool c1 = (r1 <= KK - 1) && (r1 + q1 > KK - 1);
            float cand = c0 ? e0 : (c1 ? e1 : INF);
#pragma unroll
            for (int off = 32; off; off >>= 1) cand = fminf(cand, __shfl_xor(cand, off));
            cutoff = cand;
        }
    }
    if (lane == 0) { cutArr[p] = cutoff; cntArr[p] = cnt; }
    for (int c = lane; c < cnt; c += 64) {
        float2 e = sDJ[w][c];
        unsigned j = __float_as_uint(e.y);
        bool fwd = (e.x <= cutoff);
        nbr[(size_t)p * CAP + c] = (unsigned short)(j | (fwd ? 0x8000u : 0u));
    }
}

// Kernel 2 per step, one wave per particle p (lane = h):
//  prepass: per-candidate flags (fwd from k1 bit, rev: d2 <= cutoff_j) packed in LDS
//  main:    S1[h] += 4v[h]*sech2(Ap+Dj+b1), S2[h] += 4v[h]*sech2(Aj+Dp+b1)
//  epilogue: grad_p = W1_top @ S1 + W1_bot @ S2; x_next = x - DT*grad
template <bool FIRST>
__global__ __launch_bounds__(BLOCK) void k_grad(
    const float* __restrict__ x, const float* __restrict__ pos,
    const float* __restrict__ cutArr, const int* __restrict__ cntArr,
    const unsigned short* __restrict__ nbr, const float2* __restrict__ AD,
    const float* __restrict__ W1, const float* __restrict__ b1,
    const float* __restrict__ W2, const float* __restrict__ Wout,
    float* __restrict__ xOut, float* __restrict__ posOut) {
    __shared__ float sPos[2 * NN];         // 16 KB
    __shared__ float sCut[NN];             // 8 KB
    __shared__ float sW1t[HHH * 33];       // 8.25 KB padded transpose: sW1t[h*33+f]=W1[f][h]
    __shared__ int   sJW[WPB][CAP];        // 3 KB packed candidate words
    __shared__ float sS[WPB][128];         // 4 KB
    __shared__ float sV[HHH];              // 0.25 KB  (total 39.5 KB -> 4 blocks/CU)

    int tid = threadIdx.x;
    int w = tid >> 6, h = tid & 63;
    int p = blockIdx.x * WPB + w;
    int pl = p & (NN - 1);
    int bbase = (p >> 11) << 11;

    if (FIRST) {
        for (int t = tid; t < 2 * NN; t += BLOCK)
            sPos[t] = x[(size_t)(bbase + (t >> 1)) * DD + (t & 1)];
    } else {
        for (int t = tid; t < 2 * NN; t += BLOCK) sPos[t] = pos[bbase * 2 + t];
    }
    for (int t = tid; t < NN; t += BLOCK) sCut[t] = cutArr[bbase + t];
    for (int t = tid; t < 2 * DD * HHH; t += BLOCK) {
        int f = t >> 6, hh = t & 63;
        sW1t[hh * 33 + f] = W1[t];         // pad 33: conflict-free write & read
    }
    if (tid < HHH) {                       // v = W2 @ Wout, same fma order as before
        float acc = 0.f;
        for (int c = 0; c < 32; c++) acc = fmaf(W2[tid * 32 + c], Wout[c], acc);
        sV[tid] = acc;
    }
    __syncthreads();

    float2 adp = AD[((size_t)p << 6) + h];
    float Ap = adp.x, Dp = adp.y;
    float b1h = b1[h];
    float vh4 = 4.f * sV[h];
    int cnt = cntArr[p];
    float px = sPos[2 * pl], py = sPos[2 * pl + 1];

    // ---- candidate-parallel flag prepass (d2 bit-identical to k_neighbors) ----
    for (int c = h; c < cnt; c += 64) {
        int jp = (int)nbr[(size_t)p * CAP + c];
        int jl = jp & (NN - 1);
        float d2 = dist2(px, py, sPos[2 * jl], sPos[2 * jl + 1]);
        sJW[w][c] = jl | (jp & 0x8000) | ((d2 <= sCut[jl]) ? 0x4000 : 0);
    }
    __threadfence_block();

    // ---- main loop: scalar-decoded candidate words, one dwordx2 AD load each ----
    float S1 = 0.f, S2 = 0.f;
    auto edge = [&](int sw) {
        if (sw & 0xC000) {
            int jl = sw & (NN - 1);
            float2 ad = AD[((size_t)(bbase + jl) << 6) + h];
            if (sw & 0x8000) {             // fwd: j in nbr(p)
                float z = Ap + ad.y + b1h;
                float a = __expf(-2.f * fabsf(z));
                float b = 1.f + a;
                S1 += vh4 * (a * __builtin_amdgcn_rcpf(b * b));
            }
            if (sw & 0x4000) {             // rev: p in nbr(j)
                float z = ad.x + Dp + b1h;
                float a = __expf(-2.f * fabsf(z));
                float b = 1.f + a;
                S2 += vh4 * (a * __builtin_amdgcn_rcpf(b * b));
            }
        }
    };
    const int2* sJW2 = (const int2*)&sJW[w][0];
    int c = 0;
    for (; c + 1 < cnt; c += 2) {          // 2x unroll, order preserved
        int2 ww = sJW2[c >> 1];
        edge(__builtin_amdgcn_readfirstlane(ww.x));
        edge(__builtin_amdgcn_readfirstlane(ww.y));
    }
    if (c < cnt) edge(__builtin_amdgcn_readfirstlane(sJW[w][c]));

    sS[w][h] = S1;
    sS[w][64 + h] = S2;
    __syncthreads();

    float g = 0.f;
    if (h < 32) {                          // l<16: W1_top@S1 ; 16<=l<32: W1_bot@S2
        const float* Sv = &sS[w][(h < 16) ? 0 : 64];
        float acc = 0.f;
        for (int hh = 0; hh < 64; hh++) acc = fmaf(sW1t[hh * 33 + h], Sv[hh], acc);
        g = acc;
    }
    float g2 = __shfl(g, (h + 16) & 63);
    if (h < DD) {
        float xn = x[(size_t)p * DD + h] - DT_C * (g + g2);
        xOut[(size_t)p * DD + h] = xn;
        if (h < 2) posOut[p * 2 + h] = xn;
    }
}

extern "C" void kernel_launch(void* const* d_in, const int* in_sizes, int n_in,
                              void* d_out, int out_size, void* d_ws, size_t ws_size,
                              hipStream_t stream) {
    const float* x0   = (const float*)d_in[0];
    const float* W1   = (const float*)d_in[1];
    const float* b1   = (const float*)d_in[2];
    const float* W2   = (const float*)d_in[3];
    const float* Wout = (const float*)d_in[5];
    float* out = (float*)d_out;

    // workspace layout (floats); total ~13 MB
    float* ws   = (float*)d_ws;
    float* posA = ws;                      // 32768 (dead sink for last step)
    float* posB = posA + 32768;            // 32768
    float* x1   = posB + 32768;            // 262144
    float2* AD  = (float2*)(x1 + 262144);  // 16384 x 64 float2 (8 MB), 8B-aligned
    float* cut  = (float*)(AD + 16384 * 64);  // 16384
    int*   cnt  = (int*)(cut + 16384);     // 16384
    unsigned short* nbr = (unsigned short*)(cnt + 16384);  // 16384*96

    dim3 blk(BLOCK);
    const int NBLK = (BB * NN) / WPB;      // 2048

    // step 0: x0 -> x1 (stage pos straight from x0)
    k_neighbors<true><<<NBLK, blk, 0, stream>>>(x0, nullptr, W1, nbr, cnt, cut, AD);
    k_grad<true><<<NBLK, blk, 0, stream>>>(x0, nullptr, cut, cnt, nbr, AD, W1, b1,
                                           W2, Wout, x1, posB);
    // step 1: x1 -> out
    k_neighbors<false><<<NBLK, blk, 0, stream>>>(x1, posB, W1, nbr, cnt, cut, AD);
    k_grad<false><<<NBLK, blk, 0, stream>>>(x1, posB, cut, cnt, nbr, AD, W1, b1,
                                            W2, Wout, out, posA);
}

// Round 3
// 207.205 us; speedup vs baseline: 1.3587x; 1.1263x over previous
//
#include <hip/hip_runtime.h>
#include <cstdint>
#include <cstddef>

// Problem constants (from reference setup_inputs)
#define BB   8
#define NN   2048
#define DD   16
#define HHH  64
#define KK   32
#define CAP  96          // max within-R candidates kept (mean ~36, Poisson tail safe)
#define DT_C 0.01f
#define R2_C (0.08f * 0.08f)
#define CEXP (-2.885390081777927f)   // -2*log2(e):  exp(-2|z|) = exp2(CEXP*|z|)

#define WPB   8                 // waves per block (1 particle per wave)
#define BLOCK (WPB * 64)

// Bit-deterministic distance: identical codegen in both kernels (no fma contraction),
// so k_grad's d2 matches k_neighbors' cutoff values exactly. Also bitwise symmetric.
__device__ __forceinline__ float dist2(float px, float py, float qx, float qy) {
    float dx = __fsub_rn(px, qx);
    float dy = __fsub_rn(py, qy);
    return __fadd_rn(__fmul_rn(dx, dx), __fmul_rn(dy, dy));
}

__device__ __forceinline__ int mbcnt64(unsigned long long m) {
    return (int)__builtin_amdgcn_mbcnt_hi(
        (unsigned)(m >> 32), __builtin_amdgcn_mbcnt_lo((unsigned)m, 0u));
}

// Kernel 1 per step, one wave per particle p:
//  - A_p[h] = x_p @ W1[:16], D_p[h] = x_p @ W1[16:]  -> separate A/D planes
//  - collect candidates {j : d2 < R^2, j != p} via ballot+mbcnt compaction (j-ascending)
//  - cutoff_p = 32nd smallest candidate d2 (bitonic sort; LDS rank-select if cnt>64)
//  - emit candidate list with fwd flag (d2 <= cutoff_p) in bit 15
template <bool FIRST>
__global__ __launch_bounds__(BLOCK) void k_neighbors(
    const float* __restrict__ x, const float* __restrict__ pos,
    const float* __restrict__ W1,
    unsigned short* __restrict__ nbr, int* __restrict__ cntArr,
    float* __restrict__ cutArr,
    float* __restrict__ Aplane, float* __restrict__ Dplane) {
    __shared__ float sPos[2 * NN];          // 16 KB
    __shared__ float sW1[2 * DD * HHH];     // 8 KB
    __shared__ float2 sDJ[WPB][CAP];        // 6 KB packed {d2, j-bits}

    int tid = threadIdx.x;
    int w = tid >> 6, lane = tid & 63;
    int p = blockIdx.x * WPB + w;
    int pl = p & (NN - 1);
    int bbase = (p >> 11) << 11;

    if (FIRST) {
        for (int t = tid; t < 2 * NN; t += BLOCK)
            sPos[t] = x[(size_t)(bbase + (t >> 1)) * DD + (t & 1)];
    } else {
        for (int t = tid; t < 2 * NN; t += BLOCK) sPos[t] = pos[bbase * 2 + t];
    }
    for (int t = tid; t < 2 * DD * HHH; t += BLOCK) sW1[t] = W1[t];
    __syncthreads();

    // ---- A/D precompute (lane = h), split-plane store ----
    float xv = (lane < DD) ? x[(size_t)p * DD + lane] : 0.f;
    float A = 0.f, Dv = 0.f;
#pragma unroll
    for (int f = 0; f < DD; f++) {
        float xf = __shfl(xv, f);
        A  = fmaf(xf, sW1[f * HHH + lane], A);
        Dv = fmaf(xf, sW1[(DD + f) * HHH + lane], Dv);
    }
    Aplane[((size_t)p << 6) + lane] = A;
    Dplane[((size_t)p << 6) + lane] = Dv;

    // ---- candidate collection: 4-wide chunking for LDS-load ILP ----
    float px = sPos[2 * pl], py = sPos[2 * pl + 1];
    const float2* sPos2 = (const float2*)sPos;
    int cnt = 0;
    for (int c0 = 0; c0 < NN; c0 += 256) {
        float2 q[4];
#pragma unroll
        for (int u = 0; u < 4; ++u) q[u] = sPos2[c0 + (u << 6) + lane];
#pragma unroll
        for (int u = 0; u < 4; ++u) {
            int j = c0 + (u << 6) + lane;
            float d2 = dist2(px, py, q[u].x, q[u].y);
            bool hit = (d2 < R2_C) && (j != pl);
            unsigned long long m = __ballot(hit);
            int idx = cnt + mbcnt64(m & ((1ull << lane) - 1ull) | 0ull);
            // (mask-by-prefix via mbcnt of full mask is wrong; use prefix mask)
            if (hit && idx < CAP)
                sDJ[w][idx] = make_float2(d2, __uint_as_float((unsigned)j));
            cnt += (int)__popcll(m);
        }
    }
    if (cnt > CAP) cnt = CAP;
    __threadfence_block();   // wave-local LDS RAW drain

    // ---- cutoff = K-th smallest candidate d2 (value-exact selection) ----
    float cutoff = R2_C;
    if (cnt > KK) {
        const float INF = 1e30f;
        if (cnt <= 64) {
            float v = (lane < cnt) ? sDJ[w][lane].x : INF;
#pragma unroll
            for (int k = 2; k <= 64; k <<= 1) {
#pragma unroll
                for (int j = k >> 1; j > 0; j >>= 1) {
                    float pv = __shfl_xor(v, j);
                    bool up = ((lane & k) == 0);
                    bool takeMin = (((lane & j) == 0) == up);
                    v = takeMin ? fminf(v, pv) : fmaxf(v, pv);
                }
            }
            cutoff = __shfl(v, KK - 1);   // ascending sort -> 32nd smallest
        } else {                          // cnt in (64,96]: ~never, kept for correctness
            float e0 = (lane < cnt) ? sDJ[w][lane].x : INF;
            float e1 = (lane + 64 < cnt) ? sDJ[w][lane + 64].x : INF;
            int r0 = 0, q0 = 0, r1 = 0, q1 = 0;
            for (int k = 0; k < cnt; k++) {
                float val = sDJ[w][k].x;
                r0 += (val < e0); q0 += (val == e0);
                r1 += (val < e1); q1 += (val == e1);
            }
            bool c0 = (r0 <= KK - 1) && (r0 + q0 > KK - 1);
            bool c1 = (r1 <= KK - 1) && (r1 + q1 > KK - 1);
            float cand = c0 ? e0 : (c1 ? e1 : INF);
#pragma unroll
            for (int off = 32; off; off >>= 1) cand = fminf(cand, __shfl_xor(cand, off));
            cutoff = cand;
        }
    }
    if (lane == 0) { cutArr[p] = cutoff; cntArr[p] = cnt; }
    for (int c = lane; c < cnt; c += 64) {
        float2 e = sDJ[w][c];
        unsigned j = __float_as_uint(e.y);
        bool fwd = (e.x <= cutoff);
        nbr[(size_t)p * CAP + c] = (unsigned short)(j | (fwd ? 0x8000u : 0u));
    }
}

// Kernel 2 per step, one wave per particle p (lane = h):
//  prepass: ballot-compact fwd list {j in nbr(p)} and rev list {j : p in nbr(j)}
//  main:    T1 += sech2((Ap+b1)+D_j)/4-form; T2 += sech2((Dp+b1)+A_j); S=4v*T
//  epilogue: grad_p = W1_top @ S1 + W1_bot @ S2; x_next = x - DT*grad
template <bool FIRST>
__global__ __launch_bounds__(BLOCK) void k_grad(
    const float* __restrict__ x, const float* __restrict__ pos,
    const float* __restrict__ cutArr, const int* __restrict__ cntArr,
    const unsigned short* __restrict__ nbr,
    const float* __restrict__ Aplane, const float* __restrict__ Dplane,
    const float* __restrict__ W1, const float* __restrict__ b1,
    const float* __restrict__ W2, const float* __restrict__ Wout,
    float* __restrict__ xOut, float* __restrict__ posOut) {
    __shared__ float sPos[2 * NN];            // 16 KB
    __shared__ float sCut[NN];                // 8 KB
    __shared__ float sW1t[HHH * 33];          // 8.25 KB: sW1t[hh*33+f] = W1[f][hh]
    __shared__ unsigned short sFwd[WPB][CAP]; // 1.5 KB
    __shared__ unsigned short sRev[WPB][CAP]; // 1.5 KB
    __shared__ float sS[WPB][128];            // 4 KB
    __shared__ float sV[HHH];                 // 0.25 KB  (39.5 KB -> 4 blocks/CU)

    int tid = threadIdx.x;
    int w = tid >> 6, h = tid & 63;
    int p = blockIdx.x * WPB + w;
    int pl = p & (NN - 1);
    int bbase = (p >> 11) << 11;

    if (FIRST) {
        for (int t = tid; t < 2 * NN; t += BLOCK)
            sPos[t] = x[(size_t)(bbase + (t >> 1)) * DD + (t & 1)];
    } else {
        for (int t = tid; t < 2 * NN; t += BLOCK) sPos[t] = pos[bbase * 2 + t];
    }
    for (int t = tid; t < NN; t += BLOCK) sCut[t] = cutArr[bbase + t];
    for (int t = tid; t < 2 * DD * HHH; t += BLOCK) {
        int f = t >> 6, hh = t & 63;
        sW1t[hh * 33 + f] = W1[t];            // pad 33: conflict-free write & read
    }
    if (tid < HHH) {                          // v = W2 @ Wout
        float acc = 0.f;
        for (int c = 0; c < 32; c++) acc = fmaf(W2[tid * 32 + c], Wout[c], acc);
        sV[tid] = acc;
    }
    __syncthreads();

    float b1h = b1[h];
    float Apb = Aplane[((size_t)p << 6) + h] + b1h;
    float Dpb = Dplane[((size_t)p << 6) + h] + b1h;
    float vh4 = 4.f * sV[h];
    int cnt = cntArr[p];
    float px = sPos[2 * pl], py = sPos[2 * pl + 1];
    const float2* sPos2 = (const float2*)sPos;

    // ---- prepass: split flagged candidates into fwd / rev compacted lists ----
    int mf = 0, mr = 0;
    for (int c0 = 0; c0 < cnt; c0 += 64) {
        int c = c0 + h;
        bool act = c < cnt;
        int jp = act ? (int)nbr[(size_t)p * CAP + c] : 0;
        int jl = jp & (NN - 1);
        bool fwd = act && (jp & 0x8000);
        bool rev = false;
        if (act) {
            float2 q = sPos2[jl];
            float d2 = dist2(px, py, q.x, q.y);   // bit-identical to k_neighbors
            rev = (d2 <= sCut[jl]);
        }
        unsigned long long mF = __ballot(fwd);
        int iF = mf + mbcnt64(mF & ((1ull << h) - 1ull));
        if (fwd) sFwd[w][iF] = (unsigned short)jl;
        mf += (int)__popcll(mF);
        unsigned long long mR = __ballot(rev);
        int iR = mr + mbcnt64(mR & ((1ull << h) - 1ull));
        if (rev) sRev[w][iR] = (unsigned short)jl;
        mr += (int)__popcll(mR);
    }
    __threadfence_block();

    // ---- main loops: branch-free, 8-wide unrolled, scalar-based dword gathers ----
    const float* baseD = Dplane + ((size_t)bbase << 6);
    const float* baseA = Aplane + ((size_t)bbase << 6);
    float T1 = 0.f, T2 = 0.f;

    auto edgeF = [&](unsigned jl) {
        float dj = baseD[((size_t)jl << 6) + h];
        float z = Apb + dj;
        float a = __builtin_amdgcn_exp2f(CEXP * fabsf(z));
        float bb = 1.f + a;
        T1 += a * __builtin_amdgcn_rcpf(bb * bb);
    };
    auto edgeR = [&](unsigned jl) {
        float aj = baseA[((size_t)jl << 6) + h];
        float z = Dpb + aj;
        float a = __builtin_amdgcn_exp2f(CEXP * fabsf(z));
        float bb = 1.f + a;
        T2 += a * __builtin_amdgcn_rcpf(bb * bb);
    };

    {
        const unsigned short* L = sFwd[w];
        int c = 0;
        for (; c + 8 <= mf; c += 8) {
            int4 qw = *(const int4*)(L + c);      // lane-uniform broadcast read
            unsigned w0 = (unsigned)__builtin_amdgcn_readfirstlane(qw.x);
            unsigned w1 = (unsigned)__builtin_amdgcn_readfirstlane(qw.y);
            unsigned w2 = (unsigned)__builtin_amdgcn_readfirstlane(qw.z);
            unsigned w3 = (unsigned)__builtin_amdgcn_readfirstlane(qw.w);
            edgeF(w0 & 0xffffu); edgeF(w0 >> 16);
            edgeF(w1 & 0xffffu); edgeF(w1 >> 16);
            edgeF(w2 & 0xffffu); edgeF(w2 >> 16);
            edgeF(w3 & 0xffffu); edgeF(w3 >> 16);
        }
        for (; c < mf; ++c)
            edgeF((unsigned)__builtin_amdgcn_readfirstlane((int)L[c]));
    }
    {
        const unsigned short* L = sRev[w];
        int c = 0;
        for (; c + 8 <= mr; c += 8) {
            int4 qw = *(const int4*)(L + c);
            unsigned w0 = (unsigned)__builtin_amdgcn_readfirstlane(qw.x);
            unsigned w1 = (unsigned)__builtin_amdgcn_readfirstlane(qw.y);
            unsigned w2 = (unsigned)__builtin_amdgcn_readfirstlane(qw.z);
            unsigned w3 = (unsigned)__builtin_amdgcn_readfirstlane(qw.w);
            edgeR(w0 & 0xffffu); edgeR(w0 >> 16);
            edgeR(w1 & 0xffffu); edgeR(w1 >> 16);
            edgeR(w2 & 0xffffu); edgeR(w2 >> 16);
            edgeR(w3 & 0xffffu); edgeR(w3 >> 16);
        }
        for (; c < mr; ++c)
            edgeR((unsigned)__builtin_amdgcn_readfirstlane((int)L[c]));
    }

    sS[w][h] = vh4 * T1;
    sS[w][64 + h] = vh4 * T2;
    __threadfence_block();                    // wave-local: no block barrier needed

    float g = 0.f;
    if (h < 32) {                             // l<16: W1_top@S1 ; 16<=l<32: W1_bot@S2
        const float* Sv = &sS[w][(h < 16) ? 0 : 64];
        float acc = 0.f;
        for (int hh = 0; hh < 64; hh++) acc = fmaf(sW1t[hh * 33 + h], Sv[hh], acc);
        g = acc;
    }
    float g2 = __shfl(g, (h + 16) & 63);
    if (h < DD) {
        float xn = x[(size_t)p * DD + h] - DT_C * (g + g2);
        xOut[(size_t)p * DD + h] = xn;
        if (h < 2) posOut[p * 2 + h] = xn;
    }
}

extern "C" void kernel_launch(void* const* d_in, const int* in_sizes, int n_in,
                              void* d_out, int out_size, void* d_ws, size_t ws_size,
                              hipStream_t stream) {
    const float* x0   = (const float*)d_in[0];
    const float* W1   = (const float*)d_in[1];
    const float* b1   = (const float*)d_in[2];
    const float* W2   = (const float*)d_in[3];
    const float* Wout = (const float*)d_in[5];
    float* out = (float*)d_out;

    // workspace layout (floats); total ~13 MB
    float* ws   = (float*)d_ws;
    float* posA = ws;                      // 32768 (dead sink for last step)
    float* posB = posA + 32768;            // 32768
    float* x1   = posB + 32768;            // 262144
    float* Apl  = x1 + 262144;             // 16384*64 (4 MB)
    float* Dpl  = Apl + 16384 * 64;        // 16384*64 (4 MB)
    float* cut  = Dpl + 16384 * 64;        // 16384
    int*   cnt  = (int*)(cut + 16384);     // 16384
    unsigned short* nbr = (unsigned short*)(cnt + 16384);  // 16384*96

    dim3 blk(BLOCK);
    const int NBLK = (BB * NN) / WPB;      // 2048

    // step 0: x0 -> x1 (stage pos straight from x0)
    k_neighbors<true><<<NBLK, blk, 0, stream>>>(x0, nullptr, W1, nbr, cnt, cut, Apl, Dpl);
    k_grad<true><<<NBLK, blk, 0, stream>>>(x0, nullptr, cut, cnt, nbr, Apl, Dpl,
                                           W1, b1, W2, Wout, x1, posB);
    // step 1: x1 -> out
    k_neighbors<false><<<NBLK, blk, 0, stream>>>(x1, posB, W1, nbr, cnt, cut, Apl, Dpl);
    k_grad<false><<<NBLK, blk, 0, stream>>>(x1, posB, cut, cnt, nbr, Apl, Dpl,
                                            W1, b1, W2, Wout, out, posA);
}

// Round 4
// 189.105 us; speedup vs baseline: 1.4888x; 1.0957x over previous
//
#include <hip/hip_runtime.h>
#include <cstdint>
#include <cstddef>

// Problem constants (from reference setup_inputs)
#define BB   8
#define NN   2048
#define DD   16
#define HHH  64
#define KK   32
#define CAP  96          // max within-R candidates kept (mean ~36, Poisson tail safe)
#define DT_C 0.01f
#define R2_C (0.08f * 0.08f)
#define CEXP (-2.885390081777927f)   // -2*log2(e):  exp(-2|z|) = exp2(CEXP*|z|)

#define WPB   16                // waves per block (1 particle per wave)
#define BLOCK (WPB * 64)

// Bit-deterministic distance: identical codegen in both kernels (no fma contraction),
// so k_grad's d2 matches k_neighbors' cutoff values exactly. Also bitwise symmetric.
__device__ __forceinline__ float dist2(float px, float py, float qx, float qy) {
    float dx = __fsub_rn(px, qx);
    float dy = __fsub_rn(py, qy);
    return __fadd_rn(__fmul_rn(dx, dx), __fmul_rn(dy, dy));
}

__device__ __forceinline__ int mbcnt64(unsigned long long m) {
    return (int)__builtin_amdgcn_mbcnt_hi(
        (unsigned)(m >> 32), __builtin_amdgcn_mbcnt_lo((unsigned)m, 0u));
}

// Kernel 1 per step, one wave per particle p:
//  - A_p[h] = x_p @ W1[:16], D_p[h] = x_p @ W1[16:]  -> separate A/D planes
//  - collect candidates {j : d2 < R^2, j != p} via ballot+mbcnt compaction
//  - cutoff_p = 32nd smallest candidate d2 (bitonic sort; LDS rank-select if cnt>64)
//  - emit candidate list with fwd flag (d2 <= cutoff_p) in bit 15
template <bool FIRST>
__global__ __launch_bounds__(BLOCK) void k_neighbors(
    const float* __restrict__ x, const float* __restrict__ pos,
    const float* __restrict__ W1,
    unsigned short* __restrict__ nbr, int* __restrict__ cntArr,
    float* __restrict__ cutArr,
    float* __restrict__ Aplane, float* __restrict__ Dplane) {
    __shared__ float sPos[2 * NN];          // 16 KB
    __shared__ float sW1[2 * DD * HHH];     // 8 KB
    __shared__ float2 sDJ[WPB][CAP];        // 12 KB packed {d2, j-bits}

    int tid = threadIdx.x;
    int w = tid >> 6, lane = tid & 63;
    int p = blockIdx.x * WPB + w;
    int pl = p & (NN - 1);
    int bbase = (p >> 11) << 11;

    if (FIRST) {
        for (int t = tid; t < 2 * NN; t += BLOCK)
            sPos[t] = x[(size_t)(bbase + (t >> 1)) * DD + (t & 1)];
    } else {
        for (int t = tid; t < 2 * NN; t += BLOCK) sPos[t] = pos[bbase * 2 + t];
    }
    for (int t = tid; t < 2 * DD * HHH; t += BLOCK) sW1[t] = W1[t];
    __syncthreads();

    // ---- A/D precompute (lane = h), split-plane store ----
    float xv = (lane < DD) ? x[(size_t)p * DD + lane] : 0.f;
    float A = 0.f, Dv = 0.f;
#pragma unroll
    for (int f = 0; f < DD; f++) {
        float xf = __shfl(xv, f);
        A  = fmaf(xf, sW1[f * HHH + lane], A);
        Dv = fmaf(xf, sW1[(DD + f) * HHH + lane], Dv);
    }
    Aplane[((size_t)p << 6) + lane] = A;
    Dplane[((size_t)p << 6) + lane] = Dv;

    // ---- candidate collection: 4-wide chunking for LDS-load ILP ----
    float px = sPos[2 * pl], py = sPos[2 * pl + 1];
    const float2* sPos2 = (const float2*)sPos;
    int cnt = 0;
    for (int c0 = 0; c0 < NN; c0 += 256) {
        float2 q[4];
#pragma unroll
        for (int u = 0; u < 4; ++u) q[u] = sPos2[c0 + (u << 6) + lane];
#pragma unroll
        for (int u = 0; u < 4; ++u) {
            int j = c0 + (u << 6) + lane;
            float d2 = dist2(px, py, q[u].x, q[u].y);
            bool hit = (d2 < R2_C) && (j != pl);
            unsigned long long m = __ballot(hit);
            int idx = cnt + mbcnt64(m & ((1ull << lane) - 1ull));
            if (hit && idx < CAP)
                sDJ[w][idx] = make_float2(d2, __uint_as_float((unsigned)j));
            cnt += (int)__popcll(m);
        }
    }
    if (cnt > CAP) cnt = CAP;
    __threadfence_block();   // wave-local LDS RAW drain

    // ---- cutoff = K-th smallest candidate d2 (value-exact selection) ----
    float cutoff = R2_C;
    if (cnt > KK) {
        const float INF = 1e30f;
        if (cnt <= 64) {
            float v = (lane < cnt) ? sDJ[w][lane].x : INF;
#pragma unroll
            for (int k = 2; k <= 64; k <<= 1) {
#pragma unroll
                for (int j = k >> 1; j > 0; j >>= 1) {
                    float pv = __shfl_xor(v, j);
                    bool up = ((lane & k) == 0);
                    bool takeMin = (((lane & j) == 0) == up);
                    v = takeMin ? fminf(v, pv) : fmaxf(v, pv);
                }
            }
            cutoff = __shfl(v, KK - 1);   // ascending sort -> 32nd smallest
        } else {                          // cnt in (64,96]: ~never, kept for correctness
            float e0 = (lane < cnt) ? sDJ[w][lane].x : INF;
            float e1 = (lane + 64 < cnt) ? sDJ[w][lane + 64].x : INF;
            int r0 = 0, q0 = 0, r1 = 0, q1 = 0;
            for (int k = 0; k < cnt; k++) {
                float val = sDJ[w][k].x;
                r0 += (val < e0); q0 += (val == e0);
                r1 += (val < e1); q1 += (val == e1);
            }
            bool c0 = (r0 <= KK - 1) && (r0 + q0 > KK - 1);
            bool c1 = (r1 <= KK - 1) && (r1 + q1 > KK - 1);
            float cand = c0 ? e0 : (c1 ? e1 : INF);
#pragma unroll
            for (int off = 32; off; off >>= 1) cand = fminf(cand, __shfl_xor(cand, off));
            cutoff = cand;
        }
    }
    if (lane == 0) { cutArr[p] = cutoff; cntArr[p] = cnt; }
    for (int c = lane; c < cnt; c += 64) {
        float2 e = sDJ[w][c];
        unsigned j = __float_as_uint(e.y);
        bool fwd = (e.x <= cutoff);
        nbr[(size_t)p * CAP + c] = (unsigned short)(j | (fwd ? 0x8000u : 0u));
    }
}

// Kernel 2 per step, one wave per particle p (lane = h):
//  prepass: per-candidate direct global gathers (pos[jl], cut[jl]), recompute d2
//           bit-identically, ballot-compact fwd & rev lists -- no block staging
//  main:    T1 += sech2/4((Ap+b1)+D_j); T2 += sech2/4((Dp+b1)+A_j); S = 4v*T
//  epilogue: grad_p = W1_top @ S1 + W1_bot @ S2; x_next = x - DT*grad
template <bool FIRST>
__global__ __launch_bounds__(BLOCK) void k_grad(
    const float* __restrict__ x, const float* __restrict__ pos,
    const float* __restrict__ cutArr, const int* __restrict__ cntArr,
    const unsigned short* __restrict__ nbr,
    const float* __restrict__ Aplane, const float* __restrict__ Dplane,
    const float* __restrict__ W1, const float* __restrict__ b1,
    const float* __restrict__ W2, const float* __restrict__ Wout,
    float* __restrict__ xOut, float* __restrict__ posOut) {
    __shared__ float sW1t[HHH * 33];          // 8.25 KB: sW1t[hh*33+f] = W1[f][hh]
    __shared__ unsigned short sFwd[WPB][CAP]; // 3 KB
    __shared__ unsigned short sRev[WPB][CAP]; // 3 KB
    __shared__ float sS[WPB][128];            // 8 KB
    __shared__ float sV[HHH];                 // 0.25 KB  (~22.5 KB total)

    int tid = threadIdx.x;
    int w = tid >> 6, h = tid & 63;
    int p = blockIdx.x * WPB + w;
    int bbase = (p >> 11) << 11;

    for (int t = tid; t < 2 * DD * HHH; t += BLOCK) {
        int f = t >> 6, hh = t & 63;
        sW1t[hh * 33 + f] = W1[t];            // pad 33: conflict-free write & read
    }
    if (tid < HHH) {                          // v = W2 @ Wout
        float acc = 0.f;
        for (int c = 0; c < 32; c++) acc = fmaf(W2[tid * 32 + c], Wout[c], acc);
        sV[tid] = acc;
    }
    __syncthreads();                          // the only block barrier

    float b1h = b1[h];
    float Apb = Aplane[((size_t)p << 6) + h] + b1h;
    float Dpb = Dplane[((size_t)p << 6) + h] + b1h;
    float vh4 = 4.f * sV[h];
    int cnt = cntArr[p];

    // particle p's own position (no staging)
    float px, py;
    if (FIRST) {
        float2 pp = *(const float2*)(x + (size_t)p * DD);
        px = pp.x; py = pp.y;
    } else {
        float2 pp = *(const float2*)(pos + (size_t)p * 2);
        px = pp.x; py = pp.y;
    }

    // ---- prepass: direct gathers, split into fwd / rev compacted lists ----
    int mf = 0, mr = 0;
    for (int c0 = 0; c0 < cnt; c0 += 64) {
        int c = c0 + h;
        bool act = c < cnt;
        int cc = act ? c : cnt - 1;
        int jp = (int)nbr[(size_t)p * CAP + cc];
        int jl = jp & (NN - 1);
        float2 q;
        if (FIRST) q = *(const float2*)(x + (size_t)(bbase + jl) * DD);
        else       q = *(const float2*)(pos + (size_t)(bbase + jl) * 2);
        float d2 = dist2(px, py, q.x, q.y);   // bit-identical to k_neighbors
        float cutj = cutArr[bbase + jl];
        bool fwd = act && (jp & 0x8000);
        bool rev = act && (d2 <= cutj);
        unsigned long long mF = __ballot(fwd);
        int iF = mf + mbcnt64(mF & ((1ull << h) - 1ull));
        if (fwd) sFwd[w][iF] = (unsigned short)jl;
        mf += (int)__popcll(mF);
        unsigned long long mR = __ballot(rev);
        int iR = mr + mbcnt64(mR & ((1ull << h) - 1ull));
        if (rev) sRev[w][iR] = (unsigned short)jl;
        mr += (int)__popcll(mR);
    }
    __threadfence_block();

    // ---- main loops: branch-free, 8-wide unrolled, scalar-based dword gathers ----
    const float* baseD = Dplane + ((size_t)bbase << 6);
    const float* baseA = Aplane + ((size_t)bbase << 6);
    float T1 = 0.f, T2 = 0.f;

    auto edgeF = [&](unsigned jl) {
        float dj = baseD[((size_t)jl << 6) + h];
        float z = Apb + dj;
        float a = __builtin_amdgcn_exp2f(CEXP * fabsf(z));
        float bb = 1.f + a;
        T1 += a * __builtin_amdgcn_rcpf(bb * bb);
    };
    auto edgeR = [&](unsigned jl) {
        float aj = baseA[((size_t)jl << 6) + h];
        float z = Dpb + aj;
        float a = __builtin_amdgcn_exp2f(CEXP * fabsf(z));
        float bb = 1.f + a;
        T2 += a * __builtin_amdgcn_rcpf(bb * bb);
    };

    {
        const unsigned short* L = sFwd[w];
        int c = 0;
        for (; c + 8 <= mf; c += 8) {
            int4 qw = *(const int4*)(L + c);      // lane-uniform broadcast read
            unsigned w0 = (unsigned)__builtin_amdgcn_readfirstlane(qw.x);
            unsigned w1 = (unsigned)__builtin_amdgcn_readfirstlane(qw.y);
            unsigned w2 = (unsigned)__builtin_amdgcn_readfirstlane(qw.z);
            unsigned w3 = (unsigned)__builtin_amdgcn_readfirstlane(qw.w);
            edgeF(w0 & 0xffffu); edgeF(w0 >> 16);
            edgeF(w1 & 0xffffu); edgeF(w1 >> 16);
            edgeF(w2 & 0xffffu); edgeF(w2 >> 16);
            edgeF(w3 & 0xffffu); edgeF(w3 >> 16);
        }
        for (; c < mf; ++c)
            edgeF((unsigned)__builtin_amdgcn_readfirstlane((int)L[c]));
    }
    {
        const unsigned short* L = sRev[w];
        int c = 0;
        for (; c + 8 <= mr; c += 8) {
            int4 qw = *(const int4*)(L + c);
            unsigned w0 = (unsigned)__builtin_amdgcn_readfirstlane(qw.x);
            unsigned w1 = (unsigned)__builtin_amdgcn_readfirstlane(qw.y);
            unsigned w2 = (unsigned)__builtin_amdgcn_readfirstlane(qw.z);
            unsigned w3 = (unsigned)__builtin_amdgcn_readfirstlane(qw.w);
            edgeR(w0 & 0xffffu); edgeR(w0 >> 16);
            edgeR(w1 & 0xffffu); edgeR(w1 >> 16);
            edgeR(w2 & 0xffffu); edgeR(w2 >> 16);
            edgeR(w3 & 0xffffu); edgeR(w3 >> 16);
        }
        for (; c < mr; ++c)
            edgeR((unsigned)__builtin_amdgcn_readfirstlane((int)L[c]));
    }

    sS[w][h] = vh4 * T1;
    sS[w][64 + h] = vh4 * T2;
    __threadfence_block();                    // wave-local: no block barrier needed

    float g = 0.f;
    if (h < 32) {                             // l<16: W1_top@S1 ; 16<=l<32: W1_bot@S2
        const float* Sv = &sS[w][(h < 16) ? 0 : 64];
        float acc = 0.f;
        for (int hh = 0; hh < 64; hh++) acc = fmaf(sW1t[hh * 33 + h], Sv[hh], acc);
        g = acc;
    }
    float g2 = __shfl(g, (h + 16) & 63);
    if (h < DD) {
        float xn = x[(size_t)p * DD + h] - DT_C * (g + g2);
        xOut[(size_t)p * DD + h] = xn;
        if (h < 2) posOut[p * 2 + h] = xn;
    }
}

extern "C" void kernel_launch(void* const* d_in, const int* in_sizes, int n_in,
                              void* d_out, int out_size, void* d_ws, size_t ws_size,
                              hipStream_t stream) {
    const float* x0   = (const float*)d_in[0];
    const float* W1   = (const float*)d_in[1];
    const float* b1   = (const float*)d_in[2];
    const float* W2   = (const float*)d_in[3];
    const float* Wout = (const float*)d_in[5];
    float* out = (float*)d_out;

    // workspace layout (floats); total ~13 MB
    float* ws   = (float*)d_ws;
    float* posA = ws;                      // 32768 (dead sink for last step)
    float* posB = posA + 32768;            // 32768
    float* x1   = posB + 32768;            // 262144
    float* Apl  = x1 + 262144;             // 16384*64 (4 MB)
    float* Dpl  = Apl + 16384 * 64;        // 16384*64 (4 MB)
    float* cut  = Dpl + 16384 * 64;        // 16384
    int*   cnt  = (int*)(cut + 16384);     // 16384
    unsigned short* nbr = (unsigned short*)(cnt + 16384);  // 16384*96

    dim3 blk(BLOCK);
    const int NBLK = (BB * NN) / WPB;      // 1024

    // step 0: x0 -> x1 (positions read straight from x0)
    k_neighbors<true><<<NBLK, blk, 0, stream>>>(x0, nullptr, W1, nbr, cnt, cut, Apl, Dpl);
    k_grad<true><<<NBLK, blk, 0, stream>>>(x0, nullptr, cut, cnt, nbr, Apl, Dpl,
                                           W1, b1, W2, Wout, x1, posB);
    // step 1: x1 -> out
    k_neighbors<false><<<NBLK, blk, 0, stream>>>(x1, posB, W1, nbr, cnt, cut, Apl, Dpl);
    k_grad<false><<<NBLK, blk, 0, stream>>>(x1, posB, cut, cnt, nbr, Apl, Dpl,
                                            W1, b1, W2, Wout, out, posA);
}

// Round 5
// 178.345 us; speedup vs baseline: 1.5786x; 1.0603x over previous
//
#include <hip/hip_runtime.h>
#include <cstdint>
#include <cstddef>

// Problem constants (from reference setup_inputs)
#define BB   8
#define NN   2048
#define DD   16
#define HHH  64
#define KK   32
#define CAP  96          // max within-R candidates kept (mean ~36, Poisson tail safe)
#define DT_C 0.01f
#define R2_C (0.08f * 0.08f)
#define CEXP (-2.885390081777927f)   // -2*log2(e):  exp(-2|z|) = exp2(CEXP*|z|)

#define WPB   16                // waves per block (1 particle per wave)
#define BLOCK (WPB * 64)

// Bit-deterministic distance: identical codegen in both kernels (no fma contraction),
// so k_grad's d2 matches k_neighbors' cutoff values exactly. Also bitwise symmetric.
__device__ __forceinline__ float dist2(float px, float py, float qx, float qy) {
    float dx = __fsub_rn(px, qx);
    float dy = __fsub_rn(py, qy);
    return __fadd_rn(__fmul_rn(dx, dx), __fmul_rn(dy, dy));
}

__device__ __forceinline__ int mbcnt64(unsigned long long m) {
    return (int)__builtin_amdgcn_mbcnt_hi(
        (unsigned)(m >> 32), __builtin_amdgcn_mbcnt_lo((unsigned)m, 0u));
}

// XCD-aware swizzle: batch = blockIdx & 7 so each XCD's L2 caches exactly one
// batch's pos/cut/AD slices (~1 MB < 4 MB L2). Heuristic only — correctness-free.
__device__ __forceinline__ int swizzled_particle(int blk, int w, int& bbase) {
    int vb = blk & 7, vi = blk >> 3;
    bbase = vb << 11;
    return bbase + vi * WPB + w;
}

// Kernel 1 per step, one wave per particle p:
//  - A_p[h] = x_p @ W1[:16], D_p[h] = x_p @ W1[16:]  -> separate A/D planes
//  - collect candidates {j : d2 < R^2, j != p} via ballot+mbcnt compaction
//  - cutoff_p = 32nd smallest candidate d2 (bitonic sort; LDS rank-select if cnt>64)
//  - emit candidate list with fwd flag (d2 <= cutoff_p) in bit 15
template <bool FIRST>
__global__ __launch_bounds__(BLOCK) void k_neighbors(
    const float* __restrict__ x, const float* __restrict__ pos,
    const float* __restrict__ W1,
    unsigned short* __restrict__ nbr, int* __restrict__ cntArr,
    float* __restrict__ cutArr,
    float* __restrict__ Aplane, float* __restrict__ Dplane) {
    __shared__ float sPos[2 * NN];          // 16 KB
    __shared__ float sW1[2 * DD * HHH];     // 8 KB
    __shared__ float2 sDJ[WPB][CAP];        // 12 KB packed {d2, j-bits}

    int tid = threadIdx.x;
    int w = tid >> 6, lane = tid & 63;
    int bbase;
    int p = swizzled_particle(blockIdx.x, w, bbase);
    int pl = p & (NN - 1);

    float2* sPos2w = (float2*)sPos;
    if (FIRST) {
        for (int t = tid; t < NN; t += BLOCK)
            sPos2w[t] = *(const float2*)(x + (size_t)(bbase + t) * DD);
    } else {
        for (int t = tid; t < 2 * NN; t += BLOCK) sPos[t] = pos[bbase * 2 + t];
    }
    for (int t = tid; t < 2 * DD * HHH; t += BLOCK) sW1[t] = W1[t];
    __syncthreads();

    // ---- A/D precompute (lane = h), split-plane store ----
    float xv = (lane < DD) ? x[(size_t)p * DD + lane] : 0.f;
    float A = 0.f, Dv = 0.f;
#pragma unroll
    for (int f = 0; f < DD; f++) {
        float xf = __shfl(xv, f);
        A  = fmaf(xf, sW1[f * HHH + lane], A);
        Dv = fmaf(xf, sW1[(DD + f) * HHH + lane], Dv);
    }
    Aplane[((size_t)p << 6) + lane] = A;
    Dplane[((size_t)p << 6) + lane] = Dv;

    // ---- candidate collection: 4-wide chunking for LDS-load ILP ----
    float px = sPos[2 * pl], py = sPos[2 * pl + 1];
    const float2* sPos2 = (const float2*)sPos;
    int cnt = 0;
    for (int c0 = 0; c0 < NN; c0 += 256) {
        float2 q[4];
#pragma unroll
        for (int u = 0; u < 4; ++u) q[u] = sPos2[c0 + (u << 6) + lane];
#pragma unroll
        for (int u = 0; u < 4; ++u) {
            int j = c0 + (u << 6) + lane;
            float d2 = dist2(px, py, q[u].x, q[u].y);
            bool hit = (d2 < R2_C) && (j != pl);
            unsigned long long m = __ballot(hit);
            int idx = cnt + mbcnt64(m & ((1ull << lane) - 1ull));
            if (hit && idx < CAP)
                sDJ[w][idx] = make_float2(d2, __uint_as_float((unsigned)j));
            cnt += (int)__popcll(m);
        }
    }
    if (cnt > CAP) cnt = CAP;
    __threadfence_block();   // wave-local LDS RAW drain

    // ---- cutoff = K-th smallest candidate d2 (value-exact selection) ----
    float cutoff = R2_C;
    if (cnt > KK) {
        const float INF = 1e30f;
        if (cnt <= 64) {
            float v = (lane < cnt) ? sDJ[w][lane].x : INF;
#pragma unroll
            for (int k = 2; k <= 64; k <<= 1) {
#pragma unroll
                for (int j = k >> 1; j > 0; j >>= 1) {
                    float pv = __shfl_xor(v, j);
                    bool up = ((lane & k) == 0);
                    bool takeMin = (((lane & j) == 0) == up);
                    v = takeMin ? fminf(v, pv) : fmaxf(v, pv);
                }
            }
            cutoff = __shfl(v, KK - 1);   // ascending sort -> 32nd smallest
        } else {                          // cnt in (64,96]: ~never, kept for correctness
            float e0 = (lane < cnt) ? sDJ[w][lane].x : INF;
            float e1 = (lane + 64 < cnt) ? sDJ[w][lane + 64].x : INF;
            int r0 = 0, q0 = 0, r1 = 0, q1 = 0;
            for (int k = 0; k < cnt; k++) {
                float val = sDJ[w][k].x;
                r0 += (val < e0); q0 += (val == e0);
                r1 += (val < e1); q1 += (val == e1);
            }
            bool c0 = (r0 <= KK - 1) && (r0 + q0 > KK - 1);
            bool c1 = (r1 <= KK - 1) && (r1 + q1 > KK - 1);
            float cand = c0 ? e0 : (c1 ? e1 : INF);
#pragma unroll
            for (int off = 32; off; off >>= 1) cand = fminf(cand, __shfl_xor(cand, off));
            cutoff = cand;
        }
    }
    if (lane == 0) { cutArr[p] = cutoff; cntArr[p] = cnt; }
    for (int c = lane; c < cnt; c += 64) {
        float2 e = sDJ[w][c];
        unsigned j = __float_as_uint(e.y);
        bool fwd = (e.x <= cutoff);
        nbr[(size_t)p * CAP + c] = (unsigned short)(j | (fwd ? 0x8000u : 0u));
    }
}

// Kernel 2 per step, one wave per particle p (lane = h):
//  prepass: per-candidate direct global gathers (pos[jl], cut[jl]), recompute d2
//           bit-identically, ballot-compact fwd & rev lists -- no block staging
//  main:    T1 += sech2/4((Ap+b1)+D_j); T2 += sech2/4((Dp+b1)+A_j); S = 4v*T
//  epilogue: grad_p = W1_top @ S1 + W1_bot @ S2; x_next = x - DT*grad
template <bool FIRST>
__global__ __launch_bounds__(BLOCK) void k_grad(
    const float* __restrict__ x, const float* __restrict__ pos,
    const float* __restrict__ cutArr, const int* __restrict__ cntArr,
    const unsigned short* __restrict__ nbr,
    const float* __restrict__ Aplane, const float* __restrict__ Dplane,
    const float* __restrict__ W1, const float* __restrict__ b1,
    const float* __restrict__ W2, const float* __restrict__ Wout,
    float* __restrict__ xOut, float* __restrict__ posOut) {
    __shared__ float sW1t[HHH * 33];                      // 8.25 KB
    __shared__ alignas(16) unsigned short sFwd[WPB][CAP]; // 3 KB
    __shared__ alignas(16) unsigned short sRev[WPB][CAP]; // 3 KB
    __shared__ float sS[WPB][128];                        // 8 KB
    __shared__ float sV[HHH];                             // (~22.5 KB total)

    int tid = threadIdx.x;
    int w = tid >> 6, h = tid & 63;
    int bbase;
    int p = swizzled_particle(blockIdx.x, w, bbase);

    for (int t = tid; t < 2 * DD * HHH; t += BLOCK) {
        int f = t >> 6, hh = t & 63;
        sW1t[hh * 33 + f] = W1[t];            // pad 33: conflict-free write & read
    }
    if (tid < HHH) {                          // v = W2 @ Wout
        float acc = 0.f;
        for (int c = 0; c < 32; c++) acc = fmaf(W2[tid * 32 + c], Wout[c], acc);
        sV[tid] = acc;
    }
    __syncthreads();                          // the only block barrier

    float b1h = b1[h];
    float Apb = Aplane[((size_t)p << 6) + h] + b1h;
    float Dpb = Dplane[((size_t)p << 6) + h] + b1h;
    float vh4 = 4.f * sV[h];
    int cnt = cntArr[p];

    // particle p's own position (no staging)
    float px, py;
    if (FIRST) {
        float2 pp = *(const float2*)(x + (size_t)p * DD);
        px = pp.x; py = pp.y;
    } else {
        float2 pp = *(const float2*)(pos + (size_t)p * 2);
        px = pp.x; py = pp.y;
    }

    // ---- prepass: direct gathers, split into fwd / rev compacted lists ----
    int mf = 0, mr = 0;
    for (int c0 = 0; c0 < cnt; c0 += 64) {
        int c = c0 + h;
        bool act = c < cnt;
        int cc = act ? c : cnt - 1;
        int jp = (int)nbr[(size_t)p * CAP + cc];
        int jl = jp & (NN - 1);
        float2 q;
        if (FIRST) q = *(const float2*)(x + (size_t)(bbase + jl) * DD);
        else       q = *(const float2*)(pos + (size_t)(bbase + jl) * 2);
        float d2 = dist2(px, py, q.x, q.y);   // bit-identical to k_neighbors
        float cutj = cutArr[bbase + jl];
        bool fwd = act && (jp & 0x8000);
        bool rev = act && (d2 <= cutj);
        unsigned long long mF = __ballot(fwd);
        int iF = mf + mbcnt64(mF & ((1ull << h) - 1ull));
        if (fwd) sFwd[w][iF] = (unsigned short)jl;
        mf += (int)__popcll(mF);
        unsigned long long mR = __ballot(rev);
        int iR = mr + mbcnt64(mR & ((1ull << h) - 1ull));
        if (rev) sRev[w][iR] = (unsigned short)jl;
        mr += (int)__popcll(mR);
    }
    __threadfence_block();

    // ---- main loops: branch-free, 16-deep gather batching, scalar-decoded ----
    const float* baseD = Dplane + ((size_t)bbase << 6);
    const float* baseA = Aplane + ((size_t)bbase << 6);
    float T1 = 0.f, T2 = 0.f;

    auto s2core = [&](float z) {
        float a = __builtin_amdgcn_exp2f(CEXP * fabsf(z));
        float bb = 1.f + a;
        return a * __builtin_amdgcn_rcpf(bb * bb);
    };

#define UNPACK8(Q0, Q1, U)                                            \
    unsigned U[8];                                                    \
    U[0] = (unsigned)__builtin_amdgcn_readfirstlane(Q0.x);            \
    U[1] = (unsigned)__builtin_amdgcn_readfirstlane(Q0.y);            \
    U[2] = (unsigned)__builtin_amdgcn_readfirstlane(Q0.z);            \
    U[3] = (unsigned)__builtin_amdgcn_readfirstlane(Q0.w);            \
    U[4] = (unsigned)__builtin_amdgcn_readfirstlane(Q1.x);            \
    U[5] = (unsigned)__builtin_amdgcn_readfirstlane(Q1.y);            \
    U[6] = (unsigned)__builtin_amdgcn_readfirstlane(Q1.z);            \
    U[7] = (unsigned)__builtin_amdgcn_readfirstlane(Q1.w);

    {   // fwd stream: T1 += s2(Apb + D_j)
        const unsigned short* L = sFwd[w];
        int c = 0;
        for (; c + 16 <= mf; c += 16) {
            int4 q0 = *(const int4*)(L + c);
            int4 q1 = *(const int4*)(L + c + 8);
            UNPACK8(q0, q1, u)
            float d[16];
#pragma unroll
            for (int k = 0; k < 8; ++k) {     // 16 independent gathers in flight
                d[2 * k]     = baseD[((size_t)(u[k] & 0xffffu) << 6) + h];
                d[2 * k + 1] = baseD[((size_t)(u[k] >> 16) << 6) + h];
            }
#pragma unroll
            for (int k = 0; k < 16; ++k) T1 += s2core(Apb + d[k]);
        }
        for (; c + 8 <= mf; c += 8) {
            int4 q0 = *(const int4*)(L + c);
            int4 q1 = q0;
            UNPACK8(q0, q1, u)
            float d[8];
#pragma unroll
            for (int k = 0; k < 4; ++k) {
                d[2 * k]     = baseD[((size_t)(u[k] & 0xffffu) << 6) + h];
                d[2 * k + 1] = baseD[((size_t)(u[k] >> 16) << 6) + h];
            }
#pragma unroll
            for (int k = 0; k < 8; ++k) T1 += s2core(Apb + d[k]);
        }
        for (; c < mf; ++c) {
            unsigned jl = (unsigned)__builtin_amdgcn_readfirstlane((int)L[c]);
            T1 += s2core(Apb + baseD[((size_t)jl << 6) + h]);
        }
    }
    {   // rev stream: T2 += s2(Dpb + A_j)
        const unsigned short* L = sRev[w];
        int c = 0;
        for (; c + 16 <= mr; c += 16) {
            int4 q0 = *(const int4*)(L + c);
            int4 q1 = *(const int4*)(L + c + 8);
            UNPACK8(q0, q1, u)
            float d[16];
#pragma unroll
            for (int k = 0; k < 8; ++k) {
                d[2 * k]     = baseA[((size_t)(u[k] & 0xffffu) << 6) + h];
                d[2 * k + 1] = baseA[((size_t)(u[k] >> 16) << 6) + h];
            }
#pragma unroll
            for (int k = 0; k < 16; ++k) T2 += s2core(Dpb + d[k]);
        }
        for (; c + 8 <= mr; c += 8) {
            int4 q0 = *(const int4*)(L + c);
            int4 q1 = q0;
            UNPACK8(q0, q1, u)
            float d[8];
#pragma unroll
            for (int k = 0; k < 4; ++k) {
                d[2 * k]     = baseA[((size_t)(u[k] & 0xffffu) << 6) + h];
                d[2 * k + 1] = baseA[((size_t)(u[k] >> 16) << 6) + h];
            }
#pragma unroll
            for (int k = 0; k < 8; ++k) T2 += s2core(Dpb + d[k]);
        }
        for (; c < mr; ++c) {
            unsigned jl = (unsigned)__builtin_amdgcn_readfirstlane((int)L[c]);
            T2 += s2core(Dpb + baseA[((size_t)jl << 6) + h]);
        }
    }
#undef UNPACK8

    sS[w][h] = vh4 * T1;
    sS[w][64 + h] = vh4 * T2;
    __threadfence_block();                    // wave-local: no block barrier needed

    float g = 0.f;
    if (h < 32) {                             // l<16: W1_top@S1 ; 16<=l<32: W1_bot@S2
        const float* Sv = &sS[w][(h < 16) ? 0 : 64];
        float acc = 0.f;
        for (int hh = 0; hh < 64; hh++) acc = fmaf(sW1t[hh * 33 + h], Sv[hh], acc);
        g = acc;
    }
    float g2 = __shfl(g, (h + 16) & 63);
    if (h < DD) {
        float xn = x[(size_t)p * DD + h] - DT_C * (g + g2);
        xOut[(size_t)p * DD + h] = xn;
        if (h < 2) posOut[p * 2 + h] = xn;
    }
}

extern "C" void kernel_launch(void* const* d_in, const int* in_sizes, int n_in,
                              void* d_out, int out_size, void* d_ws, size_t ws_size,
                              hipStream_t stream) {
    const float* x0   = (const float*)d_in[0];
    const float* W1   = (const float*)d_in[1];
    const float* b1   = (const float*)d_in[2];
    const float* W2   = (const float*)d_in[3];
    const float* Wout = (const float*)d_in[5];
    float* out = (float*)d_out;

    // workspace layout (floats); total ~13 MB
    float* ws   = (float*)d_ws;
    float* posA = ws;                      // 32768 (dead sink for last step)
    float* posB = posA + 32768;            // 32768
    float* x1   = posB + 32768;            // 262144
    float* Apl  = x1 + 262144;             // 16384*64 (4 MB)
    float* Dpl  = Apl + 16384 * 64;        // 16384*64 (4 MB)
    float* cut  = Dpl + 16384 * 64;        // 16384
    int*   cnt  = (int*)(cut + 16384);     // 16384
    unsigned short* nbr = (unsigned short*)(cnt + 16384);  // 16384*96

    dim3 blk(BLOCK);
    const int NBLK = (BB * NN) / WPB;      // 1024

    // step 0: x0 -> x1 (positions read straight from x0)
    k_neighbors<true><<<NBLK, blk, 0, stream>>>(x0, nullptr, W1, nbr, cnt, cut, Apl, Dpl);
    k_grad<true><<<NBLK, blk, 0, stream>>>(x0, nullptr, cut, cnt, nbr, Apl, Dpl,
                                           W1, b1, W2, Wout, x1, posB);
    // step 1: x1 -> out
    k_neighbors<false><<<NBLK, blk, 0, stream>>>(x1, posB, W1, nbr, cnt, cut, Apl, Dpl);
    k_grad<false><<<NBLK, blk, 0, stream>>>(x1, posB, cut, cnt, nbr, Apl, Dpl,
                                            W1, b1, W2, Wout, out, posA);
}